// Round 1
// baseline (749.511 us; speedup 1.0000x reference)
//
#include <hip/hip_runtime.h>

// Problem constants
constexpr int Bc = 2, Sc = 2048, Dc = 256, Hc = 8, DKc = 32;
constexpr int BH = Bc * Hc;

typedef _Float16 f16x8 __attribute__((ext_vector_type(8)));
typedef _Float16 f16x4 __attribute__((ext_vector_type(4)));
typedef float    f32x4 __attribute__((ext_vector_type(4)));

// ---------------------------------------------------------------------------
// K1: projection  out = X @ W   (X: [B*S, 256] f32, W: [256, 256] f32 d-major)
// Q/K layout: [B][H][S][DK] f16.  V layout (vtrans=1): [B][H][DK][S] f16.
// ---------------------------------------------------------------------------
__global__ __launch_bounds__(256) void proj_kernel(
    const float* __restrict__ X, const float* __restrict__ W,
    _Float16* __restrict__ out, int vtrans)
{
    constexpr int ROWS = 8;
    __shared__ float xs[ROWS][Dc];
    const int r0 = blockIdx.x * ROWS;       // global row = b*S + s
    const int t = threadIdx.x;
    #pragma unroll
    for (int i = 0; i < ROWS; ++i)
        xs[i][t] = X[(long)(r0 + i) * Dc + t];
    __syncthreads();
    float acc[ROWS];
    #pragma unroll
    for (int i = 0; i < ROWS; ++i) acc[i] = 0.f;
    for (int d = 0; d < Dc; ++d) {
        float w = W[d * Dc + t];
        #pragma unroll
        for (int i = 0; i < ROWS; ++i) acc[i] = fmaf(xs[i][d], w, acc[i]);
    }
    const int h = t >> 5, dk = t & 31;
    #pragma unroll
    for (int i = 0; i < ROWS; ++i) {
        int row = r0 + i;
        int b = row / Sc, s = row % Sc;
        long idx = vtrans ? (((long)(b * Hc + h) * DKc + dk) * Sc + s)
                          : (((long)(b * Hc + h) * Sc + s) * DKc + dk);
        out[idx] = (_Float16)acc[i];
    }
}

// ---------------------------------------------------------------------------
// K1b: relT[b][n][k] = relation[b][k][n]  (f32 -> f16, 64x64 LDS transpose)
// ---------------------------------------------------------------------------
__global__ __launch_bounds__(256) void relT_kernel(
    const float* __restrict__ rel, _Float16* __restrict__ relT)
{
    __shared__ float tile[64][65];
    const int b = blockIdx.z;
    const int k0 = blockIdx.y * 64, n0 = blockIdx.x * 64;
    const int tx = threadIdx.x & 63, ty = threadIdx.x >> 6;
    const float* src = rel + (long)b * Sc * Sc;
    #pragma unroll
    for (int i = 0; i < 16; ++i) {
        int k = i * 4 + ty;
        tile[k][tx] = src[(long)(k0 + k) * Sc + n0 + tx];
    }
    __syncthreads();
    _Float16* dst = relT + (long)b * Sc * Sc;
    #pragma unroll
    for (int i = 0; i < 16; ++i) {
        int n = i * 4 + ty;
        dst[(long)(n0 + n) * Sc + k0 + tx] = (_Float16)tile[tx][n];
    }
}

// ---------------------------------------------------------------------------
// K2: qk[bh][q][k] = (1/sqrt(32)) * sum_d Q[bh][q][d] * K[bh][k][d]  (f16 out)
// vector-FMA, 64x64 tile per block, 4x4 outputs per thread.
// ---------------------------------------------------------------------------
__global__ __launch_bounds__(256) void qk_kernel(
    const _Float16* __restrict__ Qb, const _Float16* __restrict__ Kb,
    _Float16* __restrict__ qkb)
{
    __shared__ float qs[64][33];
    __shared__ float ks[64][33];
    const int bh = blockIdx.z;
    const int q0 = blockIdx.y * 64, k0 = blockIdx.x * 64;
    const int t = threadIdx.x;
    {
        int row = t >> 2;              // 0..63
        int col = (t & 3) * 8;         // 0,8,16,24
        f16x8 qv = *(const f16x8*)&Qb[((long)bh * Sc + q0 + row) * DKc + col];
        f16x8 kv = *(const f16x8*)&Kb[((long)bh * Sc + k0 + row) * DKc + col];
        #pragma unroll
        for (int e = 0; e < 8; ++e) {
            qs[row][col + e] = (float)qv[e];
            ks[row][col + e] = (float)kv[e];
        }
    }
    __syncthreads();
    const int tx = t & 15, ty = t >> 4;
    float acc[4][4] = {};
    for (int d = 0; d < DKc; ++d) {
        float qv[4], kv[4];
        #pragma unroll
        for (int i = 0; i < 4; ++i) qv[i] = qs[ty * 4 + i][d];
        #pragma unroll
        for (int j = 0; j < 4; ++j) kv[j] = ks[tx * 4 + j][d];
        #pragma unroll
        for (int i = 0; i < 4; ++i)
            #pragma unroll
            for (int j = 0; j < 4; ++j)
                acc[i][j] = fmaf(qv[i], kv[j], acc[i][j]);
    }
    const float sc = 0.17677669529663689f;  // 1/sqrt(32)
    #pragma unroll
    for (int i = 0; i < 4; ++i) {
        int qrow = q0 + ty * 4 + i;
        f16x4 o;
        #pragma unroll
        for (int j = 0; j < 4; ++j) o[j] = (_Float16)(acc[i][j] * sc);
        *(f16x4*)&qkb[((long)bh * Sc + qrow) * Sc + k0 + tx * 4] = o;
    }
}

// ---------------------------------------------------------------------------
// K3: scores[bh][q][n] = sum_k qk[bh][q][k] * relT[b][n][k]   (raw, f32 out)
// MFMA 16x16x32_f16, BM=BN=128, BK=64, 4 waves (2x2), 4x4 frags/wave.
// ---------------------------------------------------------------------------
__global__ __launch_bounds__(256) void scores_kernel(
    const _Float16* __restrict__ qk, const _Float16* __restrict__ relT,
    float* __restrict__ scores)
{
    constexpr int LDK = 72;  // padded LDS leading dim (f16 elems)
    __shared__ _Float16 As[128][LDK];
    __shared__ _Float16 Bs[128][LDK];
    const int bh = blockIdx.z;
    const int b = bh >> 3;
    const int m0 = blockIdx.y * 128;
    const int n0 = blockIdx.x * 128;
    const _Float16* Ap = qk + (long)bh * Sc * Sc;
    const _Float16* Bp = relT + (long)b * Sc * Sc;
    const int t = threadIdx.x;
    const int lane = t & 63, wave = t >> 6;
    const int wr = wave >> 1, wc = wave & 1;
    const int lrow = t >> 3;           // 0..31
    const int lcol = (t & 7) * 8;      // 0..56
    f32x4 acc[4][4] = {};
    for (int k0 = 0; k0 < Sc; k0 += 64) {
        #pragma unroll
        for (int i = 0; i < 4; ++i) {
            int r = lrow + i * 32;
            *(f16x8*)&As[r][lcol] = *(const f16x8*)&Ap[(long)(m0 + r) * Sc + k0 + lcol];
            *(f16x8*)&Bs[r][lcol] = *(const f16x8*)&Bp[(long)(n0 + r) * Sc + k0 + lcol];
        }
        __syncthreads();
        #pragma unroll
        for (int kk = 0; kk < 2; ++kk) {
            const int kb = kk * 32 + (lane >> 4) * 8;
            f16x8 af[4], bf[4];
            #pragma unroll
            for (int m = 0; m < 4; ++m)
                af[m] = *(const f16x8*)&As[wr * 64 + m * 16 + (lane & 15)][kb];
            #pragma unroll
            for (int n = 0; n < 4; ++n)
                bf[n] = *(const f16x8*)&Bs[wc * 64 + n * 16 + (lane & 15)][kb];
            #pragma unroll
            for (int m = 0; m < 4; ++m)
                #pragma unroll
                for (int n = 0; n < 4; ++n)
                    acc[m][n] = __builtin_amdgcn_mfma_f32_16x16x32_f16(
                        af[m], bf[n], acc[m][n], 0, 0, 0);
        }
        __syncthreads();
    }
    float* outp = scores + (long)bh * Sc * Sc;
    const int c = lane & 15, g = lane >> 4;
    #pragma unroll
    for (int m = 0; m < 4; ++m)
        #pragma unroll
        for (int n = 0; n < 4; ++n)
            #pragma unroll
            for (int i = 0; i < 4; ++i) {
                int row = m0 + wr * 64 + m * 16 + g * 4 + i;
                int col = n0 + wc * 64 + n * 16 + c;
                outp[(long)row * Sc + col] = acc[m][n][i];
            }
}

// ---------------------------------------------------------------------------
// K4: masked softmax in-place over d_out attn rows; also emit f16 copy to ws.
// ---------------------------------------------------------------------------
__global__ __launch_bounds__(256) void softmax_kernel(
    float* __restrict__ attn, const unsigned char* __restrict__ mask,
    _Float16* __restrict__ attnb)
{
    __shared__ float redm[4];
    __shared__ float reds[4];
    const int row = blockIdx.x;         // bh*S + q
    const int bh = row >> 11;
    const int q = row & (Sc - 1);
    const int b = bh >> 3;
    float* p = attn + (long)row * Sc;
    _Float16* pb = attnb + (long)row * Sc;
    const unsigned char* mrow = mask + ((long)b * Sc + q) * Sc;
    const int t = threadIdx.x;
    const int lane = t & 63, w = t >> 6;
    float v[8];
    float mx = -3.0e38f;
    #pragma unroll
    for (int i = 0; i < 8; ++i) {
        int n = t + i * 256;
        float s = p[n];
        if (mrow[n]) s = -1e9f;
        v[i] = s;
        mx = fmaxf(mx, s);
    }
    for (int off = 32; off; off >>= 1) mx = fmaxf(mx, __shfl_down(mx, off));
    if (lane == 0) redm[w] = mx;
    __syncthreads();
    mx = fmaxf(fmaxf(redm[0], redm[1]), fmaxf(redm[2], redm[3]));
    float sum = 0.f;
    #pragma unroll
    for (int i = 0; i < 8; ++i) { v[i] = __expf(v[i] - mx); sum += v[i]; }
    for (int off = 32; off; off >>= 1) sum += __shfl_down(sum, off);
    if (lane == 0) reds[w] = sum;
    __syncthreads();
    sum = reds[0] + reds[1] + reds[2] + reds[3];
    const float r = 1.f / sum;
    #pragma unroll
    for (int i = 0; i < 8; ++i) {
        int n = t + i * 256;
        float a = v[i] * r;
        p[n] = a;
        pb[n] = (_Float16)a;
    }
}

// ---------------------------------------------------------------------------
// K5: att[b][q][h*32+dk] = sum_n attn[bh][q][n] * V[bh][n][dk]
// A = attn f16 (K-contig rows), B^T = Vt[bh][dk][n] (K-contig rows). MFMA.
// BM=128 (q), BN=32 (dk), BK=64; 4 waves stacked in M (32 q-rows each).
// ---------------------------------------------------------------------------
__global__ __launch_bounds__(256) void pv_kernel(
    const _Float16* __restrict__ attnb, const _Float16* __restrict__ Vt,
    float* __restrict__ att)
{
    constexpr int LDK = 72;
    __shared__ _Float16 As[128][LDK];
    __shared__ _Float16 Bs[32][LDK];
    const int bh = blockIdx.z;
    const int b = bh >> 3, h = bh & 7;
    const int m0 = blockIdx.y * 128;
    const _Float16* Ap = attnb + (long)bh * Sc * Sc;
    const _Float16* Bp = Vt + (long)bh * DKc * Sc;
    const int t = threadIdx.x, lane = t & 63, w = t >> 6;
    const int arow = t >> 3;           // 0..31
    const int acol = (t & 7) * 8;
    f32x4 acc[2][2] = {};
    for (int k0 = 0; k0 < Sc; k0 += 64) {
        #pragma unroll
        for (int i = 0; i < 4; ++i)
            *(f16x8*)&As[arow + i * 32][acol] =
                *(const f16x8*)&Ap[(long)(m0 + arow + i * 32) * Sc + k0 + acol];
        *(f16x8*)&Bs[arow][acol] = *(const f16x8*)&Bp[(long)arow * Sc + k0 + acol];
        __syncthreads();
        #pragma unroll
        for (int kk = 0; kk < 2; ++kk) {
            const int kb = kk * 32 + (lane >> 4) * 8;
            f16x8 af[2], bf[2];
            #pragma unroll
            for (int m = 0; m < 2; ++m)
                af[m] = *(const f16x8*)&As[w * 32 + m * 16 + (lane & 15)][kb];
            #pragma unroll
            for (int n = 0; n < 2; ++n)
                bf[n] = *(const f16x8*)&Bs[n * 16 + (lane & 15)][kb];
            #pragma unroll
            for (int m = 0; m < 2; ++m)
                #pragma unroll
                for (int n = 0; n < 2; ++n)
                    acc[m][n] = __builtin_amdgcn_mfma_f32_16x16x32_f16(
                        af[m], bf[n], acc[m][n], 0, 0, 0);
        }
        __syncthreads();
    }
    const int c = lane & 15, g = lane >> 4;
    #pragma unroll
    for (int m = 0; m < 2; ++m)
        #pragma unroll
        for (int n = 0; n < 2; ++n)
            #pragma unroll
            for (int i = 0; i < 4; ++i) {
                int qrow = m0 + w * 32 + m * 16 + g * 4 + i;
                int dk = n * 16 + c;
                att[((long)(b * Sc + qrow)) * Dc + h * DKc + dk] = acc[m][n][i];
            }
}

// ---------------------------------------------------------------------------
// K6: out = LayerNorm(att @ Wfc + bfc + query) * gamma + beta
// ---------------------------------------------------------------------------
__global__ __launch_bounds__(256) void out_kernel(
    const float* __restrict__ att, const float* __restrict__ Wfc,
    const float* __restrict__ bfc, const float* __restrict__ query,
    const float* __restrict__ gamma, const float* __restrict__ beta,
    float* __restrict__ out)
{
    __shared__ float xs[4][Dc];
    __shared__ float ys[4][Dc];
    const int r0 = blockIdx.x * 4;
    const int t = threadIdx.x;
    #pragma unroll
    for (int i = 0; i < 4; ++i) xs[i][t] = att[(long)(r0 + i) * Dc + t];
    __syncthreads();
    float acc[4] = {0.f, 0.f, 0.f, 0.f};
    for (int d = 0; d < Dc; ++d) {
        float wv = Wfc[d * Dc + t];
        #pragma unroll
        for (int i = 0; i < 4; ++i) acc[i] = fmaf(xs[i][d], wv, acc[i]);
    }
    const float bias = bfc[t];
    #pragma unroll
    for (int i = 0; i < 4; ++i)
        ys[i][t] = acc[i] + bias + query[(long)(r0 + i) * Dc + t];
    __syncthreads();
    const int w = t >> 6, lane = t & 63;
    float x0 = ys[w][lane], x1 = ys[w][lane + 64];
    float x2 = ys[w][lane + 128], x3 = ys[w][lane + 192];
    float sum = x0 + x1 + x2 + x3;
    float sq = x0 * x0 + x1 * x1 + x2 * x2 + x3 * x3;
    for (int off = 32; off; off >>= 1) {
        sum += __shfl_down(sum, off);
        sq  += __shfl_down(sq, off);
    }
    sum = __shfl(sum, 0);
    sq  = __shfl(sq, 0);
    const float mu = sum * (1.f / 256.f);
    const float var = sq * (1.f / 256.f) - mu * mu;
    const float rstd = rsqrtf(var + 1e-5f);
    float* orow = out + (long)(r0 + w) * Dc;
    orow[lane]       = (x0 - mu) * rstd * gamma[lane]       + beta[lane];
    orow[lane + 64]  = (x1 - mu) * rstd * gamma[lane + 64]  + beta[lane + 64];
    orow[lane + 128] = (x2 - mu) * rstd * gamma[lane + 128] + beta[lane + 128];
    orow[lane + 192] = (x3 - mu) * rstd * gamma[lane + 192] + beta[lane + 192];
}

// ---------------------------------------------------------------------------
extern "C" void kernel_launch(void* const* d_in, const int* in_sizes, int n_in,
                              void* d_out, int out_size, void* d_ws, size_t ws_size,
                              hipStream_t stream)
{
    const float* query   = (const float*)d_in[0];
    const float* key_    = (const float*)d_in[1];
    const float* value   = (const float*)d_in[2];
    const unsigned char* mask = (const unsigned char*)d_in[3];
    const float* relation = (const float*)d_in[4];
    const float* Wq  = (const float*)d_in[5];
    const float* Wk  = (const float*)d_in[6];
    const float* Wv  = (const float*)d_in[7];
    const float* Wfc = (const float*)d_in[8];
    const float* bfc = (const float*)d_in[9];
    const float* gamma = (const float*)d_in[10];
    const float* beta  = (const float*)d_in[11];

    float* out_ln   = (float*)d_out;
    float* out_attn = (float*)d_out + (size_t)Bc * Sc * Dc;

    char* ws = (char*)d_ws;
    // workspace layout (bytes), all 256B-aligned
    _Float16* Qb   = (_Float16*)(ws + 0);                 //  2 MB  [B][H][S][DK]
    _Float16* Kb   = (_Float16*)(ws + 2097152);           //  2 MB  [B][H][S][DK]
    _Float16* Vt   = (_Float16*)(ws + 4194304);           //  2 MB  [B][H][DK][S]
    _Float16* relT = (_Float16*)(ws + 6291456);           // 16.8MB [B][S][S] (n,k)
    _Float16* qkb  = (_Float16*)(ws + 23068672);          // 134 MB [BH][S][S] (reused as attn f16)
    float*    attw = (float*)   (ws + 157286400);         //  4 MB  [B*S][256]

    proj_kernel<<<dim3(Bc * Sc / 8), 256, 0, stream>>>(query, Wq, Qb, 0);
    proj_kernel<<<dim3(Bc * Sc / 8), 256, 0, stream>>>(key_, Wk, Kb, 0);
    proj_kernel<<<dim3(Bc * Sc / 8), 256, 0, stream>>>(value, Wv, Vt, 1);
    relT_kernel<<<dim3(Sc / 64, Sc / 64, Bc), 256, 0, stream>>>(relation, relT);
    qk_kernel<<<dim3(Sc / 64, Sc / 64, BH), 256, 0, stream>>>(Qb, Kb, qkb);
    scores_kernel<<<dim3(Sc / 128, Sc / 128, BH), 256, 0, stream>>>(qkb, relT, out_attn);
    softmax_kernel<<<dim3(BH * Sc), 256, 0, stream>>>(out_attn, mask, qkb);
    pv_kernel<<<dim3(1, Sc / 128, BH), 256, 0, stream>>>(qkb, Vt, attw);
    out_kernel<<<dim3(Bc * Sc / 4), 256, 0, stream>>>(attw, Wfc, bfc, query,
                                                      gamma, beta, out_ln);
}

// Round 2
// 307.285 us; speedup vs baseline: 2.4391x; 2.4391x over previous
//
#include <hip/hip_runtime.h>

// Problem constants
constexpr int Bc = 2, Sc = 2048, Dc = 256, Hc = 8, DKc = 32;
constexpr int BH = Bc * Hc;

typedef _Float16 f16x8 __attribute__((ext_vector_type(8)));
typedef float    f32x4 __attribute__((ext_vector_type(4)));

// ---------------------------------------------------------------------------
// K1: projection  out = scale * (X @ W)
// vtrans=0: out[b][h][s][dk]   vtrans=1: out[b][h][dk][s]
// ---------------------------------------------------------------------------
__global__ __launch_bounds__(256) void proj_kernel(
    const float* __restrict__ X, const float* __restrict__ W,
    _Float16* __restrict__ out, int vtrans, float scale)
{
    constexpr int ROWS = 8;
    __shared__ float xs[ROWS][Dc];
    const int r0 = blockIdx.x * ROWS;       // global row = b*S + s
    const int t = threadIdx.x;
    #pragma unroll
    for (int i = 0; i < ROWS; ++i)
        xs[i][t] = X[(long)(r0 + i) * Dc + t];
    __syncthreads();
    float acc[ROWS];
    #pragma unroll
    for (int i = 0; i < ROWS; ++i) acc[i] = 0.f;
    for (int d = 0; d < Dc; ++d) {
        float w = W[d * Dc + t];
        #pragma unroll
        for (int i = 0; i < ROWS; ++i) acc[i] = fmaf(xs[i][d], w, acc[i]);
    }
    const int h = t >> 5, dk = t & 31;
    #pragma unroll
    for (int i = 0; i < ROWS; ++i) {
        int row = r0 + i;
        int b = row / Sc, s = row % Sc;
        long idx = vtrans ? (((long)(b * Hc + h) * DKc + dk) * Sc + s)
                          : (((long)(b * Hc + h) * Sc + s) * DKc + dk);
        out[idx] = (_Float16)(acc[i] * scale);
    }
}

// ---------------------------------------------------------------------------
// K1b: relT[b][n][k] = relation[b][k][n]  (f32 -> f16, 64x64 LDS transpose)
// ---------------------------------------------------------------------------
__global__ __launch_bounds__(256) void relT_kernel(
    const float* __restrict__ rel, _Float16* __restrict__ relT)
{
    __shared__ float tile[64][65];
    const int b = blockIdx.z;
    const int k0 = blockIdx.y * 64, n0 = blockIdx.x * 64;
    const int tx = threadIdx.x & 63, ty = threadIdx.x >> 6;
    const float* src = rel + (long)b * Sc * Sc;
    #pragma unroll
    for (int i = 0; i < 16; ++i) {
        int k = i * 4 + ty;
        tile[k][tx] = src[(long)(k0 + k) * Sc + n0 + tx];
    }
    __syncthreads();
    _Float16* dst = relT + (long)b * Sc * Sc;
    #pragma unroll
    for (int i = 0; i < 16; ++i) {
        int n = i * 4 + ty;
        dst[(long)(n0 + n) * Sc + k0 + tx] = (_Float16)tile[tx][n];
    }
}

// ---------------------------------------------------------------------------
// K2: KR GEMM.  KRT[b][n][hd] = sum_k relT[b][n][k] * Kt[b][hd][k]
// (so KRT[b][n][h*32+d] = sum_k rel[b][k][n] * K[b][h][k][d])
// MFMA 16x16x32_f16, BM=BN=128, BK=64, 4 waves (2x2), 4x4 frags/wave.
// ---------------------------------------------------------------------------
__global__ __launch_bounds__(256) void kr_kernel(
    const _Float16* __restrict__ relT, const _Float16* __restrict__ Kt,
    _Float16* __restrict__ KRT)
{
    constexpr int LDK = 72;  // padded LDS leading dim (f16 elems)
    __shared__ _Float16 As[128][LDK];
    __shared__ _Float16 Bs[128][LDK];
    const int b = blockIdx.z;
    const int m0 = blockIdx.y * 128;     // n (rel col) tile
    const int n0 = blockIdx.x * 128;     // hd tile (0 or 128)
    const _Float16* Ap = relT + (long)b * Sc * Sc;
    const _Float16* Bp = Kt + (long)b * Hc * DKc * Sc;
    const int t = threadIdx.x;
    const int lane = t & 63, wave = t >> 6;
    const int wr = wave >> 1, wc = wave & 1;
    const int lrow = t >> 3;           // 0..31
    const int lcol = (t & 7) * 8;      // 0..56
    f32x4 acc[4][4] = {};
    for (int k0 = 0; k0 < Sc; k0 += 64) {
        #pragma unroll
        for (int i = 0; i < 4; ++i) {
            int r = lrow + i * 32;
            *(f16x8*)&As[r][lcol] = *(const f16x8*)&Ap[(long)(m0 + r) * Sc + k0 + lcol];
            *(f16x8*)&Bs[r][lcol] = *(const f16x8*)&Bp[(long)(n0 + r) * Sc + k0 + lcol];
        }
        __syncthreads();
        #pragma unroll
        for (int kk = 0; kk < 2; ++kk) {
            const int kb = kk * 32 + (lane >> 4) * 8;
            f16x8 af[4], bf[4];
            #pragma unroll
            for (int m = 0; m < 4; ++m)
                af[m] = *(const f16x8*)&As[wr * 64 + m * 16 + (lane & 15)][kb];
            #pragma unroll
            for (int n = 0; n < 4; ++n)
                bf[n] = *(const f16x8*)&Bs[wc * 64 + n * 16 + (lane & 15)][kb];
            #pragma unroll
            for (int m = 0; m < 4; ++m)
                #pragma unroll
                for (int n = 0; n < 4; ++n)
                    acc[m][n] = __builtin_amdgcn_mfma_f32_16x16x32_f16(
                        af[m], bf[n], acc[m][n], 0, 0, 0);
        }
        __syncthreads();
    }
    _Float16* outp = KRT + (long)b * Sc * 256;
    const int c = lane & 15, g = lane >> 4;
    #pragma unroll
    for (int m = 0; m < 4; ++m)
        #pragma unroll
        for (int n = 0; n < 4; ++n)
            #pragma unroll
            for (int i = 0; i < 4; ++i) {
                int row = m0 + wr * 64 + m * 16 + g * 4 + i;
                int col = n0 + wc * 64 + n * 16 + c;
                outp[(long)row * 256 + col] = (_Float16)acc[m][n][i];
            }
}

// ---------------------------------------------------------------------------
// K3: fused  scores = Q @ KR (K=32, one MFMA) -> mask -> softmax -> attn f32
//            out + PV (attn @ V) -> att.   Two-pass online softmax per block.
// Block: 256 thr / 4 waves; QB=64 q-rows (16/wave), NT=128 n per tile.
// ---------------------------------------------------------------------------
__global__ __launch_bounds__(256) void fused_attn_kernel(
    const _Float16* __restrict__ Qb,   // [BH][S][32], pre-scaled 1/sqrt(32)
    const _Float16* __restrict__ KRT,  // [B][S][256]
    const _Float16* __restrict__ Vt,   // [BH][32][S]
    const unsigned char* __restrict__ mask, // [B][S][S]
    float* __restrict__ attn_out,      // [BH][S][S]
    float* __restrict__ attw)          // [B*S][256]
{
    constexpr int QB = 64, NT = 128, LDP = 136;
    __shared__ _Float16 att_lds[QB][LDP];
    const int bh = blockIdx.y;
    const int b = bh >> 3, h = bh & 7;
    const int q0 = blockIdx.x * QB;
    const int t = threadIdx.x, lane = t & 63, w = t >> 6;
    const int c = lane & 15, g = lane >> 4;
    const int qr = q0 + w * 16 + g * 4;         // my rows: qr + i
    // Q fragment (covers full K=32): row = w*16 + c, k = g*8..g*8+7
    const f16x8 qf = *(const f16x8*)&Qb[((long)bh * Sc + q0 + w * 16 + c) * DKc + g * 8];
    const _Float16* krt = KRT + (long)b * Sc * 256 + h * 32;
    const unsigned char* mrow = mask + (long)b * Sc * Sc;
    const f32x4 zero = {};

    float m_i[4], l_i[4];
    #pragma unroll
    for (int i = 0; i < 4; ++i) { m_i[i] = -3.0e38f; l_i[i] = 0.f; }

    // ---- pass 1: online row max + sum ----
    for (int nt = 0; nt < Sc / NT; ++nt) {
        const int n0 = nt * NT;
        f32x4 s[8];
        #pragma unroll
        for (int nf = 0; nf < 8; ++nf) {
            f16x8 bf = *(const f16x8*)&krt[(long)(n0 + nf * 16 + c) * 256 + g * 8];
            s[nf] = __builtin_amdgcn_mfma_f32_16x16x32_f16(qf, bf, zero, 0, 0, 0);
        }
        float tmax[4];
        #pragma unroll
        for (int i = 0; i < 4; ++i) tmax[i] = -3.0e38f;
        #pragma unroll
        for (int nf = 0; nf < 8; ++nf)
            #pragma unroll
            for (int i = 0; i < 4; ++i) {
                if (mrow[(long)(qr + i) * Sc + n0 + nf * 16 + c]) s[nf][i] = -1e9f;
                tmax[i] = fmaxf(tmax[i], s[nf][i]);
            }
        #pragma unroll
        for (int off = 1; off < 16; off <<= 1)
            #pragma unroll
            for (int i = 0; i < 4; ++i)
                tmax[i] = fmaxf(tmax[i], __shfl_xor(tmax[i], off));
        #pragma unroll
        for (int i = 0; i < 4; ++i) {
            float mn = fmaxf(m_i[i], tmax[i]);
            float esum = 0.f;
            #pragma unroll
            for (int nf = 0; nf < 8; ++nf) esum += __expf(s[nf][i] - mn);
            #pragma unroll
            for (int off = 1; off < 16; off <<= 1) esum += __shfl_xor(esum, off);
            l_i[i] = l_i[i] * __expf(m_i[i] - mn) + esum;
            m_i[i] = mn;
        }
    }
    float rinv[4];
    #pragma unroll
    for (int i = 0; i < 4; ++i) rinv[i] = 1.f / l_i[i];

    // ---- pass 2: recompute, emit attn f32 + f16(LDS), PV-accumulate ----
    f32x4 acc[2] = {};
    float* aout = attn_out + (long)bh * Sc * Sc;
    for (int nt = 0; nt < Sc / NT; ++nt) {
        const int n0 = nt * NT;
        f32x4 s[8];
        #pragma unroll
        for (int nf = 0; nf < 8; ++nf) {
            f16x8 bf = *(const f16x8*)&krt[(long)(n0 + nf * 16 + c) * 256 + g * 8];
            s[nf] = __builtin_amdgcn_mfma_f32_16x16x32_f16(qf, bf, zero, 0, 0, 0);
        }
        #pragma unroll
        for (int nf = 0; nf < 8; ++nf)
            #pragma unroll
            for (int i = 0; i < 4; ++i) {
                float sv = s[nf][i];
                if (mrow[(long)(qr + i) * Sc + n0 + nf * 16 + c]) sv = -1e9f;
                float a = __expf(sv - m_i[i]) * rinv[i];
                aout[(long)(qr + i) * Sc + n0 + nf * 16 + c] = a;
                att_lds[w * 16 + g * 4 + i][nf * 16 + c] = (_Float16)a;
            }
        __syncthreads();
        #pragma unroll
        for (int ks = 0; ks < 4; ++ks) {
            f16x8 af = *(const f16x8*)&att_lds[w * 16 + c][ks * 32 + g * 8];
            #pragma unroll
            for (int nb = 0; nb < 2; ++nb) {
                f16x8 vf = *(const f16x8*)&Vt[((long)bh * DKc + nb * 16 + c) * Sc + n0 + ks * 32 + g * 8];
                acc[nb] = __builtin_amdgcn_mfma_f32_16x16x32_f16(af, vf, acc[nb], 0, 0, 0);
            }
        }
        __syncthreads();
    }
    #pragma unroll
    for (int nb = 0; nb < 2; ++nb)
        #pragma unroll
        for (int i = 0; i < 4; ++i)
            attw[(long)(b * Sc + qr + i) * Dc + h * 32 + nb * 16 + c] = acc[nb][i];
}

// ---------------------------------------------------------------------------
// K4: out = LayerNorm(att @ Wfc + bfc + query) * gamma + beta
// ---------------------------------------------------------------------------
__global__ __launch_bounds__(256) void out_kernel(
    const float* __restrict__ att, const float* __restrict__ Wfc,
    const float* __restrict__ bfc, const float* __restrict__ query,
    const float* __restrict__ gamma, const float* __restrict__ beta,
    float* __restrict__ out)
{
    __shared__ float xs[4][Dc];
    __shared__ float ys[4][Dc];
    const int r0 = blockIdx.x * 4;
    const int t = threadIdx.x;
    #pragma unroll
    for (int i = 0; i < 4; ++i) xs[i][t] = att[(long)(r0 + i) * Dc + t];
    __syncthreads();
    float acc[4] = {0.f, 0.f, 0.f, 0.f};
    for (int d = 0; d < Dc; ++d) {
        float wv = Wfc[d * Dc + t];
        #pragma unroll
        for (int i = 0; i < 4; ++i) acc[i] = fmaf(xs[i][d], wv, acc[i]);
    }
    const float bias = bfc[t];
    #pragma unroll
    for (int i = 0; i < 4; ++i)
        ys[i][t] = acc[i] + bias + query[(long)(r0 + i) * Dc + t];
    __syncthreads();
    const int w = t >> 6, lane = t & 63;
    float x0 = ys[w][lane], x1 = ys[w][lane + 64];
    float x2 = ys[w][lane + 128], x3 = ys[w][lane + 192];
    float sum = x0 + x1 + x2 + x3;
    float sq = x0 * x0 + x1 * x1 + x2 * x2 + x3 * x3;
    for (int off = 32; off; off >>= 1) {
        sum += __shfl_down(sum, off);
        sq  += __shfl_down(sq, off);
    }
    sum = __shfl(sum, 0);
    sq  = __shfl(sq, 0);
    const float mu = sum * (1.f / 256.f);
    const float var = sq * (1.f / 256.f) - mu * mu;
    const float rstd = rsqrtf(var + 1e-5f);
    float* orow = out + (long)(r0 + w) * Dc;
    orow[lane]       = (x0 - mu) * rstd * gamma[lane]       + beta[lane];
    orow[lane + 64]  = (x1 - mu) * rstd * gamma[lane + 64]  + beta[lane + 64];
    orow[lane + 128] = (x2 - mu) * rstd * gamma[lane + 128] + beta[lane + 128];
    orow[lane + 192] = (x3 - mu) * rstd * gamma[lane + 192] + beta[lane + 192];
}

// ---------------------------------------------------------------------------
extern "C" void kernel_launch(void* const* d_in, const int* in_sizes, int n_in,
                              void* d_out, int out_size, void* d_ws, size_t ws_size,
                              hipStream_t stream)
{
    const float* query   = (const float*)d_in[0];
    const float* key_    = (const float*)d_in[1];
    const float* value   = (const float*)d_in[2];
    const unsigned char* mask = (const unsigned char*)d_in[3];
    const float* relation = (const float*)d_in[4];
    const float* Wq  = (const float*)d_in[5];
    const float* Wk  = (const float*)d_in[6];
    const float* Wv  = (const float*)d_in[7];
    const float* Wfc = (const float*)d_in[8];
    const float* bfc = (const float*)d_in[9];
    const float* gamma = (const float*)d_in[10];
    const float* beta  = (const float*)d_in[11];

    float* out_ln   = (float*)d_out;
    float* out_attn = (float*)d_out + (size_t)Bc * Sc * Dc;

    char* ws = (char*)d_ws;
    _Float16* Qb   = (_Float16*)(ws + 0);          //  2 MB [BH][S][32]
    _Float16* Kt   = (_Float16*)(ws + 2097152);    //  2 MB [B][H][32][S] == [b][hd][k]
    _Float16* Vt   = (_Float16*)(ws + 4194304);    //  2 MB [BH][32][S]
    _Float16* relT = (_Float16*)(ws + 6291456);    // 16.8 MB [B][S][S] (n,k)
    _Float16* KRT  = (_Float16*)(ws + 23068672);   //  2 MB [B][S][256] (n, hd)
    float*    attw = (float*)   (ws + 25165824);   //  4 MB [B*S][256]

    const float qscale = 0.17677669529663689f;  // 1/sqrt(32)
    proj_kernel<<<dim3(Bc * Sc / 8), 256, 0, stream>>>(query, Wq, Qb, 0, qscale);
    proj_kernel<<<dim3(Bc * Sc / 8), 256, 0, stream>>>(key_, Wk, Kt, 1, 1.0f);
    proj_kernel<<<dim3(Bc * Sc / 8), 256, 0, stream>>>(value, Wv, Vt, 1, 1.0f);
    relT_kernel<<<dim3(Sc / 64, Sc / 64, Bc), 256, 0, stream>>>(relation, relT);
    kr_kernel<<<dim3(2, Sc / 128, Bc), 256, 0, stream>>>(relT, Kt, KRT);
    fused_attn_kernel<<<dim3(Sc / 64, BH), 256, 0, stream>>>(
        Qb, KRT, Vt, mask, out_attn, attw);
    out_kernel<<<dim3(Bc * Sc / 4), 256, 0, stream>>>(attw, Wfc, bfc, query,
                                                      gamma, beta, out_ln);
}